// Round 2
// baseline (707.946 us; speedup 1.0000x reference)
//
#include <hip/hip_runtime.h>
#include <hip/hip_bf16.h>

// R6b: attack attn latency-boundness (MfmaUtil 11.6%, VALUBusy 8% -> ~80% stall).
// (1) raw s_barrier + lgkmcnt(0) (no vmcnt drain) so prefetches cross barriers;
// (2) cross-phase prefetch: X tiles + next-jt K issued after Phase A, in flight
//     through softmax; depth-2 register rings inside the MFMA loops;
// (3) nontemporal Q-stage loads + out stores (keep shared K/X windows L2-hot);
// (4) dependent-MFMA pair reorder in Phase D; (5) skip O-rescale when fac==1;
// (6) s_setprio around MFMA clusters.
// R6->R6b: __builtin_nontemporal_load needs a clang ext_vector ptr, not HIP float4.

typedef _Float16 f16;
typedef float f32x4 __attribute__((ext_vector_type(4)));
typedef _Float16 f16x8 __attribute__((ext_vector_type(8)));

#define MFMAH(A, B, C) __builtin_amdgcn_mfma_f32_16x16x32_f16((A), (B), (C), 0, 0, 0)

static constexpr int B_ = 8;
static constexpr int L_ = 2048;
static constexpr int D_ = 1024;
#define NEGF (-1e30f)

// lgkmcnt(0) before the barrier: my LDS writes are visible to the group when I
// arrive. Raw s_barrier does NOT drain vmcnt -> global prefetches stay in
// flight. Empty asm after = compiler fence so post-barrier LDS reads can't hoist.
#define BARRIER()                                          \
  do {                                                     \
    asm volatile("s_waitcnt lgkmcnt(0)" ::: "memory");     \
    __builtin_amdgcn_s_barrier();                          \
    asm volatile("" ::: "memory");                         \
  } while (0)

// ---------------- K0: transpose x[B][L][D] fp32 -> xT[B][D][L] f16 ----------------
__global__ __launch_bounds__(256) void transpose_kernel(const float* __restrict__ x,
                                                        f16* __restrict__ xT) {
  __shared__ f16 t[32][40];
  const int b = blockIdx.z;
  const int j0 = blockIdx.x << 5, d0 = blockIdx.y << 5;
  const int tid = threadIdx.x;
  const int r = tid >> 3, c = (tid & 7) << 2;
  float4 v = *(const float4*)&x[((size_t)(b * L_ + j0 + r)) * D_ + d0 + c];
  t[r][c + 0] = (f16)v.x; t[r][c + 1] = (f16)v.y;
  t[r][c + 2] = (f16)v.z; t[r][c + 3] = (f16)v.w;
  __syncthreads();
  union { f16 h[4]; uint2 u; } o;
  o.h[0] = t[c + 0][r]; o.h[1] = t[c + 1][r];
  o.h[2] = t[c + 2][r]; o.h[3] = t[c + 3][r];
  *(uint2*)&xT[((size_t)(b * D_ + d0 + r)) * L_ + j0 + c] = o.u;
}

// ---------------- K1: proj = relu(x @ W^T + b), f16 GEMM 64x64 tile ----------------
__global__ __launch_bounds__(256, 2) void proj_kernel(const float* __restrict__ x,
                                                      const float* __restrict__ W,
                                                      const float* __restrict__ bias,
                                                      f16* __restrict__ proj) {
  const int m0 = blockIdx.x << 6, n0 = blockIdx.y << 6;
  __shared__ f16 As[64 * 40], Bs[64 * 40];
  const int tid = threadIdx.x;
  const int wave = tid >> 6, lane = tid & 63;
  const int wr = wave >> 1, wc = wave & 1;
  const int quad = lane >> 4, l16 = lane & 15;
  const int srow = tid >> 2, scol = (tid & 3) << 3;

  f32x4 acc[2][2];
#pragma unroll
  for (int mt = 0; mt < 2; ++mt)
#pragma unroll
    for (int nt = 0; nt < 2; ++nt) acc[mt][nt] = (f32x4){0.f, 0.f, 0.f, 0.f};

  const float* xrow = &x[(size_t)(m0 + srow) * D_];
  const float* wrow = &W[(size_t)(n0 + srow) * D_];

  for (int kc = 0; kc < D_; kc += 32) {
    {
      float4 va = *(const float4*)&xrow[kc + scol];
      float4 vb = *(const float4*)&xrow[kc + scol + 4];
      union { f16 h[8]; uint4 u; } H;
      H.h[0] = (f16)va.x; H.h[1] = (f16)va.y; H.h[2] = (f16)va.z; H.h[3] = (f16)va.w;
      H.h[4] = (f16)vb.x; H.h[5] = (f16)vb.y; H.h[6] = (f16)vb.z; H.h[7] = (f16)vb.w;
      *(uint4*)&As[srow * 40 + scol] = H.u;
      float4 wa = *(const float4*)&wrow[kc + scol];
      float4 wb = *(const float4*)&wrow[kc + scol + 4];
      H.h[0] = (f16)wa.x; H.h[1] = (f16)wa.y; H.h[2] = (f16)wa.z; H.h[3] = (f16)wa.w;
      H.h[4] = (f16)wb.x; H.h[5] = (f16)wb.y; H.h[6] = (f16)wb.z; H.h[7] = (f16)wb.w;
      *(uint4*)&Bs[srow * 40 + scol] = H.u;
    }
    __syncthreads();
    f16x8 a0 = *(const f16x8*)&As[(wr * 32 + l16) * 40 + quad * 8];
    f16x8 a1 = *(const f16x8*)&As[(wr * 32 + 16 + l16) * 40 + quad * 8];
    f16x8 b0 = *(const f16x8*)&Bs[(wc * 32 + l16) * 40 + quad * 8];
    f16x8 b1 = *(const f16x8*)&Bs[(wc * 32 + 16 + l16) * 40 + quad * 8];
    acc[0][0] = MFMAH(a0, b0, acc[0][0]);
    acc[0][1] = MFMAH(a0, b1, acc[0][1]);
    acc[1][0] = MFMAH(a1, b0, acc[1][0]);
    acc[1][1] = MFMAH(a1, b1, acc[1][1]);
    __syncthreads();
  }
#pragma unroll
  for (int mt = 0; mt < 2; ++mt) {
#pragma unroll
    for (int nt = 0; nt < 2; ++nt) {
      const int n = n0 + wc * 32 + nt * 16 + l16;
      const float bv = bias[n];
#pragma unroll
      for (int r = 0; r < 4; ++r) {
        const int m = m0 + wr * 32 + mt * 16 + quad * 4 + r;
        proj[(size_t)m * D_ + n] = (f16)fmaxf(acc[mt][nt][r] + bv, 0.f);
      }
    }
  }
}

// ---------------- K2: fused flash attention, f16, latency-overlapped ----------------
// LDS = 66048 (Qs) + 9728 (Ss) + 4608 (Ps) + 384 = 78.9 KB -> 2 blocks/CU.
// Register budget note: acc = 128 acc-regs + ~130 VGPR; depth-2 rings are the
// max that fits under the 256/wave (2 waves/SIMD) cliff.
__global__ __launch_bounds__(256, 2) void attn_kernel(const f16* __restrict__ proj,
                                                      const f16* __restrict__ xT,
                                                      const int* __restrict__ xmask,
                                                      float* __restrict__ out) {
  // XCD-pinned swizzle: blockIdx.x % 8 = XCD; batch b pinned to XCD b.
  const int b = blockIdx.x & 7;
  const int i0 = (blockIdx.x >> 3) << 5;
  const int tid = threadIdx.x;
  const int wave = tid >> 6, lane = tid & 63;
  const int quad = lane >> 4, l16 = lane & 15;
  const int nbase = wave << 8;

  __shared__ f16 Qs[32 * 1032];
  __shared__ float Ss[32 * 76];
  __shared__ f16 Ps[32 * 72];
  __shared__ float m_s[32], l_s[32], fac_s[32];

  // K pipeline prologue for jt=0 (in flight across Q staging + barrier).
  f16x8 kq[2][2];
  {
    const f16* Krow0 = proj + (size_t)(b * L_ + (wave << 4) + l16) * D_;
#pragma unroll
    for (int p = 0; p < 2; ++p) {
      kq[p][0] = *(const f16x8*)&Krow0[(p << 6) + quad * 8];
      kq[p][1] = *(const f16x8*)&Krow0[(p << 6) + 32 + quad * 8];
    }
  }

  // Stage Q nontemporally: Q is read once per block; don't let the 4 MB/XCD
  // staging burst evict the shared per-jt K/X windows from the 4 MiB L2.
  const f16* Qg = proj + ((size_t)(b * L_ + i0)) * D_;
#pragma unroll 4
  for (int idx = tid; idx < 32 * 128; idx += 256) {
    const int r = idx >> 7, c = (idx & 127) << 3;
    *(f32x4*)&Qs[r * 1032 + c] =
        __builtin_nontemporal_load((const f32x4*)&Qg[(size_t)r * D_ + c]);
  }
  if (tid < 32) { m_s[tid] = NEGF; l_s[tid] = 0.f; }

  f32x4 acc[2][16];
#pragma unroll
  for (int mt = 0; mt < 2; ++mt)
#pragma unroll
    for (int nt = 0; nt < 16; ++nt) acc[mt][nt] = (f32x4){0.f, 0.f, 0.f, 0.f};

  BARRIER();

  const f16* Xg = xT + (size_t)b * D_ * L_;
  f16x8 xp[2][2];

  for (int jt = 0; jt < 32; ++jt) {
    const int j0 = jt << 6;
    const int jglob = j0 + (wave << 4) + l16;
    const bool masked = (xmask[b * L_ + jglob] != 0);
    const f16* Krow = proj + (size_t)(b * L_ + jglob) * D_;

    // ---- Phase A: S = Q K^T, depth-2 K ring (slots pre-filled last iter) ----
    f32x4 s0a = {0.f, 0.f, 0.f, 0.f}, s0b = {0.f, 0.f, 0.f, 0.f};
    f32x4 s1a = {0.f, 0.f, 0.f, 0.f}, s1b = {0.f, 0.f, 0.f, 0.f};
#pragma unroll
    for (int ks = 0; ks < 16; ++ks) {
      const f16x8 c0 = kq[ks & 1][0], c1 = kq[ks & 1][1];
      if (ks < 14) {
        kq[ks & 1][0] = *(const f16x8*)&Krow[((ks + 2) << 6) + quad * 8];
        kq[ks & 1][1] = *(const f16x8*)&Krow[((ks + 2) << 6) + 32 + quad * 8];
      }
      const int kc = ks << 6;
      f16x8 qa0 = *(const f16x8*)&Qs[l16 * 1032 + kc + quad * 8];
      f16x8 qa1 = *(const f16x8*)&Qs[(16 + l16) * 1032 + kc + quad * 8];
      f16x8 qb0 = *(const f16x8*)&Qs[l16 * 1032 + kc + 32 + quad * 8];
      f16x8 qb1 = *(const f16x8*)&Qs[(16 + l16) * 1032 + kc + 32 + quad * 8];
      __builtin_amdgcn_s_setprio(1);
      s0a = MFMAH(qa0, c0, s0a);
      s1a = MFMAH(qa1, c0, s1a);
      s0b = MFMAH(qb0, c1, s0b);
      s1b = MFMAH(qb1, c1, s1b);
      __builtin_amdgcn_s_setprio(0);
    }

    // ---- Cross-phase prefetch (raw barriers below do NOT drain vmcnt):
    // this jt's first X tiles (used in Phase D, 2 barriers away) and next
    // jt's first K steps (used in next Phase A) ride through softmax.
#pragma unroll
    for (int p = 0; p < 2; ++p) {
      const f16* Xn = Xg + (size_t)(nbase + (p << 4) + l16) * L_ + j0;
      xp[p][0] = *(const f16x8*)&Xn[quad * 8];
      xp[p][1] = *(const f16x8*)&Xn[32 + quad * 8];
    }
    if (jt + 1 < 32) {
      const f16* Kn = proj + (size_t)(b * L_ + ((jt + 1) << 6) + (wave << 4) + l16) * D_;
#pragma unroll
      for (int p = 0; p < 2; ++p) {
        kq[p][0] = *(const f16x8*)&Kn[(p << 6) + quad * 8];
        kq[p][1] = *(const f16x8*)&Kn[(p << 6) + 32 + quad * 8];
      }
    }

    // ---- Phase B: diag-zero, padding mask, stash S ----
#pragma unroll
    for (int mt = 0; mt < 2; ++mt) {
#pragma unroll
      for (int r = 0; r < 4; ++r) {
        const int irow = (mt << 4) + (quad << 2) + r;
        float v = mt ? (s1a[r] + s1b[r]) : (s0a[r] + s0b[r]);
        if (i0 + irow == jglob) v = 0.f;
        if (masked) v = NEGF;
        Ss[irow * 76 + (wave << 4) + l16] = v;
      }
    }
    BARRIER();

    // ---- Phase C: online softmax (8 threads/row) ----
    {
      const int row = tid >> 3, part = tid & 7;
      const float* srow = &Ss[row * 76 + (part << 3)];
      const float4 sA = *(const float4*)srow;
      const float4 sB = *(const float4*)(srow + 4);
      float mx = fmaxf(fmaxf(fmaxf(sA.x, sA.y), fmaxf(sA.z, sA.w)),
                       fmaxf(fmaxf(sB.x, sB.y), fmaxf(sB.z, sB.w)));
      mx = fmaxf(mx, __shfl_xor(mx, 1));
      mx = fmaxf(mx, __shfl_xor(mx, 2));
      mx = fmaxf(mx, __shfl_xor(mx, 4));
      const float m_old = m_s[row];
      const float m_new = fmaxf(m_old, mx);
      float p[8];
      p[0] = __expf(sA.x - m_new); p[1] = __expf(sA.y - m_new);
      p[2] = __expf(sA.z - m_new); p[3] = __expf(sA.w - m_new);
      p[4] = __expf(sB.x - m_new); p[5] = __expf(sB.y - m_new);
      p[6] = __expf(sB.z - m_new); p[7] = __expf(sB.w - m_new);
      float sum = ((p[0] + p[1]) + (p[2] + p[3])) + ((p[4] + p[5]) + (p[6] + p[7]));
      sum += __shfl_xor(sum, 1);
      sum += __shfl_xor(sum, 2);
      sum += __shfl_xor(sum, 4);
      // fac == 1.0f EXACTLY when the running max didn't move -> Phase D can
      // skip the 128-mul rescale pass (the common case once max stabilizes).
      const float fac = (mx > m_old) ? __expf(m_old - m_new) : 1.0f;
      if (part == 0) {
        m_s[row] = m_new;
        l_s[row] = l_s[row] * fac + sum;
        fac_s[row] = fac;
      }
      union { f16 h[8]; uint4 u; } hp;
#pragma unroll
      for (int i = 0; i < 8; ++i) hp.h[i] = (f16)p[i];
      *(uint4*)&Ps[row * 72 + (part << 3)] = hp.u;
    }
    BARRIER();

    // ---- Phase D: conditional rescale, then O += P @ X (depth-2 X ring) ----
    float facr[2][4];
#pragma unroll
    for (int mt = 0; mt < 2; ++mt)
#pragma unroll
      for (int r = 0; r < 4; ++r) facr[mt][r] = fac_s[(mt << 4) + (quad << 2) + r];
    bool needR = false;
#pragma unroll
    for (int mt = 0; mt < 2; ++mt)
#pragma unroll
      for (int r = 0; r < 4; ++r) needR |= (facr[mt][r] != 1.0f);
    if (__any(needR)) {
#pragma unroll
      for (int mt = 0; mt < 2; ++mt)
#pragma unroll
        for (int nt = 0; nt < 16; ++nt)
#pragma unroll
          for (int r = 0; r < 4; ++r) acc[mt][nt][r] *= facr[mt][r];
    }

    f16x8 pa[2][2];
#pragma unroll
    for (int mt = 0; mt < 2; ++mt)
#pragma unroll
      for (int kt = 0; kt < 2; ++kt)
        pa[mt][kt] = *(const f16x8*)&Ps[((mt << 4) + l16) * 72 + (kt << 5) + quad * 8];

#pragma unroll
    for (int nt = 0; nt < 16; ++nt) {
      const f16x8 c0 = xp[nt & 1][0], c1 = xp[nt & 1][1];
      if (nt < 14) {
        const f16* Xn = Xg + (size_t)(nbase + ((nt + 2) << 4) + l16) * L_ + j0;
        xp[nt & 1][0] = *(const f16x8*)&Xn[quad * 8];
        xp[nt & 1][1] = *(const f16x8*)&Xn[32 + quad * 8];
      }
      __builtin_amdgcn_s_setprio(1);
      acc[0][nt] = MFMAH(pa[0][0], c0, acc[0][nt]);
      acc[1][nt] = MFMAH(pa[1][0], c0, acc[1][nt]);
      acc[0][nt] = MFMAH(pa[0][1], c1, acc[0][nt]);
      acc[1][nt] = MFMAH(pa[1][1], c1, acc[1][nt]);
      __builtin_amdgcn_s_setprio(0);
    }
  }

  // ---- epilogue: out = O / l (nontemporal: never re-read) ----
  float inv[2][4];
#pragma unroll
  for (int mt = 0; mt < 2; ++mt)
#pragma unroll
    for (int r = 0; r < 4; ++r) inv[mt][r] = 1.0f / l_s[(mt << 4) + (quad << 2) + r];
#pragma unroll
  for (int mt = 0; mt < 2; ++mt) {
#pragma unroll
    for (int nt = 0; nt < 16; ++nt) {
#pragma unroll
      for (int r = 0; r < 4; ++r) {
        const int row = i0 + (mt << 4) + (quad << 2) + r;
        const int col = nbase + (nt << 4) + l16;
        __builtin_nontemporal_store(acc[mt][nt][r] * inv[mt][r],
                                    &out[((size_t)(b * L_ + row)) * D_ + col]);
      }
    }
  }
}

extern "C" void kernel_launch(void* const* d_in, const int* in_sizes, int n_in,
                              void* d_out, int out_size, void* d_ws, size_t ws_size,
                              hipStream_t stream) {
  const float* x = (const float*)d_in[0];
  const int* xmask = (const int*)d_in[1];
  const float* W = (const float*)d_in[2];
  const float* bias = (const float*)d_in[3];
  float* out = (float*)d_out;

  const size_t elems = (size_t)B_ * L_ * D_;
  if (ws_size < 2 * elems * sizeof(f16)) return;
  f16* proj = (f16*)d_ws;
  f16* xT = proj + elems;

  transpose_kernel<<<dim3(L_ / 32, D_ / 32, B_), 256, 0, stream>>>(x, xT);
  proj_kernel<<<dim3((B_ * L_) / 64, D_ / 64), 256, 0, stream>>>(x, W, bias, proj);
  attn_kernel<<<dim3((L_ / 32) * B_), 256, 0, stream>>>(proj, xT, xmask, out);
}

// Round 3
// 629.038 us; speedup vs baseline: 1.1254x; 1.1254x over previous
//
#include <hip/hip_runtime.h>
#include <hip/hip_bf16.h>

// R7: attn UNCHANGED (R6b-verified 487us; latency-prefetch theory twice-null).
// Rebuild proj: current 64x64 f32-staged GEMM re-reads x 16x in f32 (~2 GB L2/L3
// traffic, ~170-200us). New: pre-cast x->x16 (in transpose, which already holds
// the values) and W->W16 (tiny kernel), both scratch-placed in the OUT buffer
// (attn fully overwrites it later); then m93-style 128x128/BK32/4-wave/4x4-acc
// f16 GEMM with stride-40 LDS padding. Predicted proj ~60-90us, total ~600-630.

typedef _Float16 f16;
typedef float f32x4 __attribute__((ext_vector_type(4)));
typedef _Float16 f16x8 __attribute__((ext_vector_type(8)));

#define MFMAH(A, B, C) __builtin_amdgcn_mfma_f32_16x16x32_f16((A), (B), (C), 0, 0, 0)

static constexpr int B_ = 8;
static constexpr int L_ = 2048;
static constexpr int D_ = 1024;
#define NEGF (-1e30f)

#define BARRIER()                                          \
  do {                                                     \
    asm volatile("s_waitcnt lgkmcnt(0)" ::: "memory");     \
    __builtin_amdgcn_s_barrier();                          \
    asm volatile("" ::: "memory");                         \
  } while (0)

// ---------------- K0: transpose x[B][L][D] fp32 -> xT[B][D][L] f16, plus x16 ----------------
// Also emits x16 (row-major f16 cast of x) for the proj GEMM: the f32 tile is
// already in registers here, so the cast costs only 33 MB of extra stores.
__global__ __launch_bounds__(256) void transpose_kernel(const float* __restrict__ x,
                                                        f16* __restrict__ xT,
                                                        f16* __restrict__ x16) {
  __shared__ f16 t[32][40];
  const int b = blockIdx.z;
  const int j0 = blockIdx.x << 5, d0 = blockIdx.y << 5;
  const int tid = threadIdx.x;
  const int r = tid >> 3, c = (tid & 7) << 2;
  float4 v = *(const float4*)&x[((size_t)(b * L_ + j0 + r)) * D_ + d0 + c];
  t[r][c + 0] = (f16)v.x; t[r][c + 1] = (f16)v.y;
  t[r][c + 2] = (f16)v.z; t[r][c + 3] = (f16)v.w;
  union { f16 h[4]; uint2 u; } xc;
  xc.h[0] = (f16)v.x; xc.h[1] = (f16)v.y;
  xc.h[2] = (f16)v.z; xc.h[3] = (f16)v.w;
  *(uint2*)&x16[((size_t)(b * L_ + j0 + r)) * D_ + d0 + c] = xc.u;
  __syncthreads();
  union { f16 h[4]; uint2 u; } o;
  o.h[0] = t[c + 0][r]; o.h[1] = t[c + 1][r];
  o.h[2] = t[c + 2][r]; o.h[3] = t[c + 3][r];
  *(uint2*)&xT[((size_t)(b * D_ + d0 + r)) * L_ + j0 + c] = o.u;
}

// ---------------- K0b: W (f32, DxD) -> W16 (f16) ----------------
__global__ __launch_bounds__(256) void wcast_kernel(const float* __restrict__ W,
                                                    f16* __restrict__ W16) {
  const int i = (blockIdx.x * 256 + threadIdx.x) << 3;
  float4 a = *(const float4*)&W[i];
  float4 c = *(const float4*)&W[i + 4];
  union { f16 h[8]; uint4 u; } H;
  H.h[0] = (f16)a.x; H.h[1] = (f16)a.y; H.h[2] = (f16)a.z; H.h[3] = (f16)a.w;
  H.h[4] = (f16)c.x; H.h[5] = (f16)c.y; H.h[6] = (f16)c.z; H.h[7] = (f16)c.w;
  *(uint4*)&W16[i] = H.u;
}

// ---------------- K1: proj = relu(x16 @ W16^T + b), 128x128 tile, BK=32 ----------------
// m93-structure: 4 waves in 2x2, each owns a 64x64 sub-tile (4x4 16x16 frags).
// LDS stride 40 f16 (80 B): 16B-aligned b128 rows, breaks power-of-2 bank aliasing.
__global__ __launch_bounds__(256, 2) void proj_kernel(const f16* __restrict__ x16,
                                                      const f16* __restrict__ W16,
                                                      const float* __restrict__ bias,
                                                      f16* __restrict__ proj) {
  const int m0 = blockIdx.x << 7, n0 = blockIdx.y << 7;
  __shared__ f16 As[128 * 40], Bs[128 * 40];
  const int tid = threadIdx.x;
  const int w = tid >> 6, lane = tid & 63;
  const int wr = w >> 1, wc = w & 1;
  const int quad = lane >> 4, l16 = lane & 15;
  // staging map: thread t covers row t>>1 (0..127), cols (t&1)*16 .. +15 (32B)
  const int srow = tid >> 1, scol = (tid & 1) << 4;

  f32x4 acc[4][4];
#pragma unroll
  for (int i = 0; i < 4; ++i)
#pragma unroll
    for (int j = 0; j < 4; ++j) acc[i][j] = (f32x4){0.f, 0.f, 0.f, 0.f};

  const f16* ga = &x16[(size_t)(m0 + srow) * D_ + scol];
  const f16* gb = &W16[(size_t)(n0 + srow) * D_ + scol];
  f16* la = &As[srow * 40 + scol];
  f16* lb = &Bs[srow * 40 + scol];

  for (int kc = 0; kc < D_; kc += 32) {
    {
      uint4 a0 = *(const uint4*)&ga[kc];
      uint4 a1 = *(const uint4*)&ga[kc + 8];
      uint4 b0 = *(const uint4*)&gb[kc];
      uint4 b1 = *(const uint4*)&gb[kc + 8];
      *(uint4*)&la[0] = a0;
      *(uint4*)&la[8] = a1;
      *(uint4*)&lb[0] = b0;
      *(uint4*)&lb[8] = b1;
    }
    __syncthreads();
    f16x8 af[4], bf[4];
#pragma unroll
    for (int i = 0; i < 4; ++i) {
      af[i] = *(const f16x8*)&As[((wr << 6) + (i << 4) + l16) * 40 + (quad << 3)];
      bf[i] = *(const f16x8*)&Bs[((wc << 6) + (i << 4) + l16) * 40 + (quad << 3)];
    }
#pragma unroll
    for (int i = 0; i < 4; ++i)
#pragma unroll
      for (int j = 0; j < 4; ++j) acc[i][j] = MFMAH(af[i], bf[j], acc[i][j]);
    __syncthreads();
  }

#pragma unroll
  for (int j = 0; j < 4; ++j) {
    const int n = n0 + (wc << 6) + (j << 4) + l16;
    const float bv = bias[n];
#pragma unroll
    for (int i = 0; i < 4; ++i) {
      const int mb = m0 + (wr << 6) + (i << 4) + (quad << 2);
#pragma unroll
      for (int r = 0; r < 4; ++r) {
        proj[(size_t)(mb + r) * D_ + n] = (f16)fmaxf(acc[i][j][r] + bv, 0.f);
      }
    }
  }
}

// ---------------- K2: fused flash attention (UNCHANGED, verified 487us) ----------------
__global__ __launch_bounds__(256, 2) void attn_kernel(const f16* __restrict__ proj,
                                                      const f16* __restrict__ xT,
                                                      const int* __restrict__ xmask,
                                                      float* __restrict__ out) {
  const int b = blockIdx.x & 7;
  const int i0 = (blockIdx.x >> 3) << 5;
  const int tid = threadIdx.x;
  const int wave = tid >> 6, lane = tid & 63;
  const int quad = lane >> 4, l16 = lane & 15;
  const int nbase = wave << 8;

  __shared__ f16 Qs[32 * 1032];
  __shared__ float Ss[32 * 76];
  __shared__ f16 Ps[32 * 72];
  __shared__ float m_s[32], l_s[32], fac_s[32];

  f16x8 kq[2][2];
  {
    const f16* Krow0 = proj + (size_t)(b * L_ + (wave << 4) + l16) * D_;
#pragma unroll
    for (int p = 0; p < 2; ++p) {
      kq[p][0] = *(const f16x8*)&Krow0[(p << 6) + quad * 8];
      kq[p][1] = *(const f16x8*)&Krow0[(p << 6) + 32 + quad * 8];
    }
  }

  const f16* Qg = proj + ((size_t)(b * L_ + i0)) * D_;
#pragma unroll 4
  for (int idx = tid; idx < 32 * 128; idx += 256) {
    const int r = idx >> 7, c = (idx & 127) << 3;
    *(f32x4*)&Qs[r * 1032 + c] =
        __builtin_nontemporal_load((const f32x4*)&Qg[(size_t)r * D_ + c]);
  }
  if (tid < 32) { m_s[tid] = NEGF; l_s[tid] = 0.f; }

  f32x4 acc[2][16];
#pragma unroll
  for (int mt = 0; mt < 2; ++mt)
#pragma unroll
    for (int nt = 0; nt < 16; ++nt) acc[mt][nt] = (f32x4){0.f, 0.f, 0.f, 0.f};

  BARRIER();

  const f16* Xg = xT + (size_t)b * D_ * L_;
  f16x8 xp[2][2];

  for (int jt = 0; jt < 32; ++jt) {
    const int j0 = jt << 6;
    const int jglob = j0 + (wave << 4) + l16;
    const bool masked = (xmask[b * L_ + jglob] != 0);
    const f16* Krow = proj + (size_t)(b * L_ + jglob) * D_;

    f32x4 s0a = {0.f, 0.f, 0.f, 0.f}, s0b = {0.f, 0.f, 0.f, 0.f};
    f32x4 s1a = {0.f, 0.f, 0.f, 0.f}, s1b = {0.f, 0.f, 0.f, 0.f};
#pragma unroll
    for (int ks = 0; ks < 16; ++ks) {
      const f16x8 c0 = kq[ks & 1][0], c1 = kq[ks & 1][1];
      if (ks < 14) {
        kq[ks & 1][0] = *(const f16x8*)&Krow[((ks + 2) << 6) + quad * 8];
        kq[ks & 1][1] = *(const f16x8*)&Krow[((ks + 2) << 6) + 32 + quad * 8];
      }
      const int kc = ks << 6;
      f16x8 qa0 = *(const f16x8*)&Qs[l16 * 1032 + kc + quad * 8];
      f16x8 qa1 = *(const f16x8*)&Qs[(16 + l16) * 1032 + kc + quad * 8];
      f16x8 qb0 = *(const f16x8*)&Qs[l16 * 1032 + kc + 32 + quad * 8];
      f16x8 qb1 = *(const f16x8*)&Qs[(16 + l16) * 1032 + kc + 32 + quad * 8];
      __builtin_amdgcn_s_setprio(1);
      s0a = MFMAH(qa0, c0, s0a);
      s1a = MFMAH(qa1, c0, s1a);
      s0b = MFMAH(qb0, c1, s0b);
      s1b = MFMAH(qb1, c1, s1b);
      __builtin_amdgcn_s_setprio(0);
    }

#pragma unroll
    for (int p = 0; p < 2; ++p) {
      const f16* Xn = Xg + (size_t)(nbase + (p << 4) + l16) * L_ + j0;
      xp[p][0] = *(const f16x8*)&Xn[quad * 8];
      xp[p][1] = *(const f16x8*)&Xn[32 + quad * 8];
    }
    if (jt + 1 < 32) {
      const f16* Kn = proj + (size_t)(b * L_ + ((jt + 1) << 6) + (wave << 4) + l16) * D_;
#pragma unroll
      for (int p = 0; p < 2; ++p) {
        kq[p][0] = *(const f16x8*)&Kn[(p << 6) + quad * 8];
        kq[p][1] = *(const f16x8*)&Kn[(p << 6) + 32 + quad * 8];
      }
    }

#pragma unroll
    for (int mt = 0; mt < 2; ++mt) {
#pragma unroll
      for (int r = 0; r < 4; ++r) {
        const int irow = (mt << 4) + (quad << 2) + r;
        float v = mt ? (s1a[r] + s1b[r]) : (s0a[r] + s0b[r]);
        if (i0 + irow == jglob) v = 0.f;
        if (masked) v = NEGF;
        Ss[irow * 76 + (wave << 4) + l16] = v;
      }
    }
    BARRIER();

    {
      const int row = tid >> 3, part = tid & 7;
      const float* srow = &Ss[row * 76 + (part << 3)];
      const float4 sA = *(const float4*)srow;
      const float4 sB = *(const float4*)(srow + 4);
      float mx = fmaxf(fmaxf(fmaxf(sA.x, sA.y), fmaxf(sA.z, sA.w)),
                       fmaxf(fmaxf(sB.x, sB.y), fmaxf(sB.z, sB.w)));
      mx = fmaxf(mx, __shfl_xor(mx, 1));
      mx = fmaxf(mx, __shfl_xor(mx, 2));
      mx = fmaxf(mx, __shfl_xor(mx, 4));
      const float m_old = m_s[row];
      const float m_new = fmaxf(m_old, mx);
      float p[8];
      p[0] = __expf(sA.x - m_new); p[1] = __expf(sA.y - m_new);
      p[2] = __expf(sA.z - m_new); p[3] = __expf(sA.w - m_new);
      p[4] = __expf(sB.x - m_new); p[5] = __expf(sB.y - m_new);
      p[6] = __expf(sB.z - m_new); p[7] = __expf(sB.w - m_new);
      float sum = ((p[0] + p[1]) + (p[2] + p[3])) + ((p[4] + p[5]) + (p[6] + p[7]));
      sum += __shfl_xor(sum, 1);
      sum += __shfl_xor(sum, 2);
      sum += __shfl_xor(sum, 4);
      const float fac = (mx > m_old) ? __expf(m_old - m_new) : 1.0f;
      if (part == 0) {
        m_s[row] = m_new;
        l_s[row] = l_s[row] * fac + sum;
        fac_s[row] = fac;
      }
      union { f16 h[8]; uint4 u; } hp;
#pragma unroll
      for (int i = 0; i < 8; ++i) hp.h[i] = (f16)p[i];
      *(uint4*)&Ps[row * 72 + (part << 3)] = hp.u;
    }
    BARRIER();

    float facr[2][4];
#pragma unroll
    for (int mt = 0; mt < 2; ++mt)
#pragma unroll
      for (int r = 0; r < 4; ++r) facr[mt][r] = fac_s[(mt << 4) + (quad << 2) + r];
    bool needR = false;
#pragma unroll
    for (int mt = 0; mt < 2; ++mt)
#pragma unroll
      for (int r = 0; r < 4; ++r) needR |= (facr[mt][r] != 1.0f);
    if (__any(needR)) {
#pragma unroll
      for (int mt = 0; mt < 2; ++mt)
#pragma unroll
        for (int nt = 0; nt < 16; ++nt)
#pragma unroll
          for (int r = 0; r < 4; ++r) acc[mt][nt][r] *= facr[mt][r];
    }

    f16x8 pa[2][2];
#pragma unroll
    for (int mt = 0; mt < 2; ++mt)
#pragma unroll
      for (int kt = 0; kt < 2; ++kt)
        pa[mt][kt] = *(const f16x8*)&Ps[((mt << 4) + l16) * 72 + (kt << 5) + quad * 8];

#pragma unroll
    for (int nt = 0; nt < 16; ++nt) {
      const f16x8 c0 = xp[nt & 1][0], c1 = xp[nt & 1][1];
      if (nt < 14) {
        const f16* Xn = Xg + (size_t)(nbase + ((nt + 2) << 4) + l16) * L_ + j0;
        xp[nt & 1][0] = *(const f16x8*)&Xn[quad * 8];
        xp[nt & 1][1] = *(const f16x8*)&Xn[32 + quad * 8];
      }
      __builtin_amdgcn_s_setprio(1);
      acc[0][nt] = MFMAH(pa[0][0], c0, acc[0][nt]);
      acc[1][nt] = MFMAH(pa[1][0], c0, acc[1][nt]);
      acc[0][nt] = MFMAH(pa[0][1], c1, acc[0][nt]);
      acc[1][nt] = MFMAH(pa[1][1], c1, acc[1][nt]);
      __builtin_amdgcn_s_setprio(0);
    }
  }

  float inv[2][4];
#pragma unroll
  for (int mt = 0; mt < 2; ++mt)
#pragma unroll
    for (int r = 0; r < 4; ++r) inv[mt][r] = 1.0f / l_s[(mt << 4) + (quad << 2) + r];
#pragma unroll
  for (int mt = 0; mt < 2; ++mt) {
#pragma unroll
    for (int nt = 0; nt < 16; ++nt) {
#pragma unroll
      for (int r = 0; r < 4; ++r) {
        const int row = i0 + (mt << 4) + (quad << 2) + r;
        const int col = nbase + (nt << 4) + l16;
        __builtin_nontemporal_store(acc[mt][nt][r] * inv[mt][r],
                                    &out[((size_t)(b * L_ + row)) * D_ + col]);
      }
    }
  }
}

extern "C" void kernel_launch(void* const* d_in, const int* in_sizes, int n_in,
                              void* d_out, int out_size, void* d_ws, size_t ws_size,
                              hipStream_t stream) {
  const float* x = (const float*)d_in[0];
  const int* xmask = (const int*)d_in[1];
  const float* W = (const float*)d_in[2];
  const float* bias = (const float*)d_in[3];
  float* out = (float*)d_out;

  const size_t elems = (size_t)B_ * L_ * D_;  // 16M
  if (ws_size < 2 * elems * sizeof(f16)) return;
  f16* proj = (f16*)d_ws;
  f16* xT = proj + elems;

  // Scratch in the OUT buffer (64 MB f32): x16 (32 MB) + W16 (2 MB).
  // attn_kernel fully overwrites out afterwards, so this is dead by readback.
  f16* x16 = (f16*)d_out;
  f16* W16 = x16 + elems;

  transpose_kernel<<<dim3(L_ / 32, D_ / 32, B_), 256, 0, stream>>>(x, xT, x16);
  wcast_kernel<<<dim3((D_ * D_) / (256 * 8)), 256, 0, stream>>>(W, W16);
  proj_kernel<<<dim3((B_ * L_) / 128, D_ / 128), 256, 0, stream>>>(x16, W16, bias, proj);
  attn_kernel<<<dim3((L_ / 32) * B_), 256, 0, stream>>>(proj, xT, xmask, out);
}

// Round 5
// 498.812 us; speedup vs baseline: 1.4193x; 1.2611x over previous
//
#include <hip/hip_runtime.h>
#include <hip/hip_bf16.h>

// R9: 3-GEMM pipeline with EXACT f32 scores (fixes R8's 0.198 absmax = f16
// rounding of ~160-magnitude scores). S computed in 4 row-chunks of 32MB f32
// living in out[0,32M); softmax reads f32, compacts normalized P to f16 in
// place (lda=4096); PV (gload_lds both operands) writes O16 to out[32M,64M);
// expand bounces through ws (proj/xT dead) to dodge in-place expansion races.
// All GEMMs share the R8 template (128x128, BK=64, xor-swizzled LDS both
// sides, global_load_lds w16) + 1-D grid making bid%8 constant across n-tiles
// of an (m,batch) panel -> A-panels XCD-L2-resident under round-robin dispatch.

typedef _Float16 f16;
typedef float f32x4 __attribute__((ext_vector_type(4)));
typedef _Float16 f16x8 __attribute__((ext_vector_type(8)));

#define MFMAH(A, B, C) __builtin_amdgcn_mfma_f32_16x16x32_f16((A), (B), (C), 0, 0, 0)

static constexpr int B_ = 8;
static constexpr int L_ = 2048;
static constexpr int D_ = 1024;
static constexpr int CH_ = 512;  // chunk rows per batch (S f32 chunk = 32MB)

__device__ __forceinline__ void gload16(const f16* g, f16* l) {
  __builtin_amdgcn_global_load_lds(
      (const __attribute__((address_space(1))) void*)g,
      (__attribute__((address_space(3))) void*)l, 16, 0, 0);
}

// ---------------- K0: transpose x -> xT f16, plus x16 f16 ----------------
__global__ __launch_bounds__(256) void transpose_kernel(const float* __restrict__ x,
                                                        f16* __restrict__ xT,
                                                        f16* __restrict__ x16) {
  __shared__ f16 t[32][40];
  const int b = blockIdx.z;
  const int j0 = blockIdx.x << 5, d0 = blockIdx.y << 5;
  const int tid = threadIdx.x;
  const int r = tid >> 3, c = (tid & 7) << 2;
  float4 v = *(const float4*)&x[((size_t)(b * L_ + j0 + r)) * D_ + d0 + c];
  t[r][c + 0] = (f16)v.x; t[r][c + 1] = (f16)v.y;
  t[r][c + 2] = (f16)v.z; t[r][c + 3] = (f16)v.w;
  union { f16 h[4]; uint2 u; } xc;
  xc.h[0] = (f16)v.x; xc.h[1] = (f16)v.y;
  xc.h[2] = (f16)v.z; xc.h[3] = (f16)v.w;
  *(uint2*)&x16[((size_t)(b * L_ + j0 + r)) * D_ + d0 + c] = xc.u;
  __syncthreads();
  union { f16 h[4]; uint2 u; } o;
  o.h[0] = t[c + 0][r]; o.h[1] = t[c + 1][r];
  o.h[2] = t[c + 2][r]; o.h[3] = t[c + 3][r];
  *(uint2*)&xT[((size_t)(b * D_ + d0 + r)) * L_ + j0 + c] = o.u;
}

// ---------------- K0b: W f32 -> W16 ----------------
__global__ __launch_bounds__(256) void wcast_kernel(const float* __restrict__ W,
                                                    f16* __restrict__ W16) {
  const int i = (blockIdx.x * 256 + threadIdx.x) << 3;
  float4 a = *(const float4*)&W[i];
  float4 c = *(const float4*)&W[i + 4];
  union { f16 h[8]; uint4 u; } H;
  H.h[0] = (f16)a.x; H.h[1] = (f16)a.y; H.h[2] = (f16)a.z; H.h[3] = (f16)a.w;
  H.h[4] = (f16)c.x; H.h[5] = (f16)c.y; H.h[6] = (f16)c.z; H.h[7] = (f16)c.w;
  *(uint4*)&W16[i] = H.u;
}

// ---------------- Template GEMM: C = A(MxK) @ B(NxK)^T ----------------
// MODE 0: proj (bias+relu, f16 C). MODE 1: S chunk (f32 C, diag-zero + mask).
// MODE 2: PV (plain f16 C).
// 1-D grid: bid = nt*nbz + z*mTiles + mt, nbz = mTiles*Z (multiple of 8) so
// bid%8 is constant across nt for fixed (z,mt): A-panel stays on one XCD L2.
template <int MODE>
__global__ __launch_bounds__(256, 2) void gemm128_kernel(
    const f16* __restrict__ A, const f16* __restrict__ Bm, void* __restrict__ Cv,
    int lda, int ldb, int ldc, int K, int mTiles, int nbz,
    size_t aBatch, size_t bBatch, size_t cBatch, int rowOff,
    const float* __restrict__ bias, const int* __restrict__ xmask) {
  const int bid = blockIdx.x;
  const int nt = bid / nbz;
  const int rem = bid - nt * nbz;
  const int z = rem / mTiles;
  const int mt = rem - z * mTiles;
  const int m0 = mt << 7, n0 = nt << 7;

  const f16* Ab = A + (size_t)z * aBatch;
  const f16* Bb = Bm + (size_t)z * bBatch;

  __shared__ f16 As[128 * 64], Bs[128 * 64];

  const int tid = threadIdx.x;
  const int w = tid >> 6, lane = tid & 63;
  const int wr = w >> 1, wc = w & 1;
  const int quad = lane >> 4, l16 = lane & 15;

  const int srow0 = w << 5;
  const int lrow = lane >> 3;   // 0..7
  const int lchunk = lane & 7;  // 16B chunk 0..7

  f32x4 acc[4][4];
#pragma unroll
  for (int i = 0; i < 4; ++i)
#pragma unroll
    for (int j = 0; j < 4; ++j) acc[i][j] = (f32x4){0.f, 0.f, 0.f, 0.f};

  for (int kc = 0; kc < K; kc += 64) {
#pragma unroll
    for (int u = 0; u < 4; ++u) {
      const int r = srow0 + (u << 3) + lrow;
      const int ca = (lchunk ^ (r & 7)) << 3;  // pre-swizzled source chunk
      gload16(&Ab[(size_t)(m0 + r) * lda + kc + ca], &As[(srow0 + (u << 3)) << 6]);
      gload16(&Bb[(size_t)(n0 + r) * ldb + kc + ca], &Bs[(srow0 + (u << 3)) << 6]);
    }
    __syncthreads();  // drains vmcnt -> staged data visible

    f16x8 af[4], bf[4];
#pragma unroll
    for (int h = 0; h < 2; ++h) {
#pragma unroll
      for (int i = 0; i < 4; ++i) {
        const int ra = (wr << 6) + (i << 4) + l16;
        af[i] = *(const f16x8*)&As[(ra << 6) + ((((h << 2) + quad) ^ (ra & 7)) << 3)];
        const int rb = (wc << 6) + (i << 4) + l16;
        bf[i] = *(const f16x8*)&Bs[(rb << 6) + ((((h << 2) + quad) ^ (rb & 7)) << 3)];
      }
#pragma unroll
      for (int i = 0; i < 4; ++i)
#pragma unroll
        for (int j = 0; j < 4; ++j) acc[i][j] = MFMAH(af[i], bf[j], acc[i][j]);
    }
    __syncthreads();
  }

  float* Cf = (float*)Cv + (MODE == 1 ? (size_t)z * cBatch : 0);
  f16* Ch = (f16*)Cv + (MODE != 1 ? (size_t)z * cBatch : 0);

#pragma unroll
  for (int j = 0; j < 4; ++j) {
    const int n = n0 + (wc << 6) + (j << 4) + l16;
    float bv = 0.f;
    bool msk = false;
    if (MODE == 0) bv = bias[n];
    if (MODE == 1) msk = (xmask[z * L_ + n] != 0);
#pragma unroll
    for (int i = 0; i < 4; ++i) {
      const int mb = m0 + (wr << 6) + (i << 4) + (quad << 2);
#pragma unroll
      for (int r = 0; r < 4; ++r) {
        float v = acc[i][j][r];
        if (MODE == 0) {
          Ch[(size_t)(mb + r) * ldc + n] = (f16)fmaxf(v + bv, 0.f);
        } else if (MODE == 1) {
          if (rowOff + mb + r == n) v = 0.f;  // diagonal zero
          if (msk) v = -1e30f;                // padding mask
          Cf[(size_t)(mb + r) * ldc + n] = v;
        } else {
          Ch[(size_t)(mb + r) * ldc + n] = (f16)v;
        }
      }
    }
  }
}

// ---------------- Row softmax: read f32 row, compact normalized P to f16 in place ----------------
// P16 row occupies the FIRST HALF of the row's f32 slot -> lda 4096 f16 for PV.
// Safe: one block owns the row; all S reads precede the reduction barriers,
// all P writes follow them.
__global__ __launch_bounds__(256) void softmax_kernel(float* __restrict__ S) {
  const size_t row = blockIdx.x;
  float* Sp = S + row * 2048;
  f16* Pp = (f16*)Sp;
  const int tid = threadIdx.x;
  const float4 sA = *(const float4*)&Sp[tid * 8];
  const float4 sB = *(const float4*)&Sp[tid * 8 + 4];
  float f[8];
  f[0] = sA.x; f[1] = sA.y; f[2] = sA.z; f[3] = sA.w;
  f[4] = sB.x; f[5] = sB.y; f[6] = sB.z; f[7] = sB.w;
  float mx = fmaxf(fmaxf(fmaxf(f[0], f[1]), fmaxf(f[2], f[3])),
                   fmaxf(fmaxf(f[4], f[5]), fmaxf(f[6], f[7])));
#pragma unroll
  for (int off = 1; off < 64; off <<= 1) mx = fmaxf(mx, __shfl_xor(mx, off));
  __shared__ float redm[4], reds[4];
  const int wv = tid >> 6;
  if ((tid & 63) == 0) redm[wv] = mx;
  __syncthreads();
  mx = fmaxf(fmaxf(redm[0], redm[1]), fmaxf(redm[2], redm[3]));
  float s = 0.f;
#pragma unroll
  for (int i = 0; i < 8; ++i) { f[i] = __expf(f[i] - mx); s += f[i]; }
#pragma unroll
  for (int off = 1; off < 64; off <<= 1) s += __shfl_xor(s, off);
  if ((tid & 63) == 0) reds[wv] = s;
  __syncthreads();
  s = (reds[0] + reds[1]) + (reds[2] + reds[3]);
  const float inv = 1.0f / s;
  f16x8 o;
#pragma unroll
  for (int i = 0; i < 8; ++i) o[i] = (f16)(f[i] * inv);
  *(f16x8*)&Pp[tid * 8] = o;
}

// ---------------- Expand O16 -> f32 (into ws), then copy ws -> out ----------------
__global__ __launch_bounds__(256) void expand_kernel(const f16* __restrict__ O16,
                                                     float* __restrict__ dst) {
  const size_t idx = ((size_t)blockIdx.x * 256 + threadIdx.x) << 3;
  f16x8 v = *(const f16x8*)&O16[idx];
  float4 a, b;
  a.x = (float)v[0]; a.y = (float)v[1]; a.z = (float)v[2]; a.w = (float)v[3];
  b.x = (float)v[4]; b.y = (float)v[5]; b.z = (float)v[6]; b.w = (float)v[7];
  *(float4*)&dst[idx] = a;
  *(float4*)&dst[idx + 4] = b;
}

__global__ __launch_bounds__(256) void copy_kernel(const float* __restrict__ src,
                                                   float* __restrict__ dst) {
  const size_t idx = ((size_t)blockIdx.x * 256 + threadIdx.x) << 3;
  float4 a = *(const float4*)&src[idx];
  float4 b = *(const float4*)&src[idx + 4];
  *(float4*)&dst[idx] = a;
  *(float4*)&dst[idx + 4] = b;
}

extern "C" void kernel_launch(void* const* d_in, const int* in_sizes, int n_in,
                              void* d_out, int out_size, void* d_ws, size_t ws_size,
                              hipStream_t stream) {
  const float* x = (const float*)d_in[0];
  const int* xmask = (const int*)d_in[1];
  const float* W = (const float*)d_in[2];
  const float* bias = (const float*)d_in[3];
  float* out = (float*)d_out;

  const size_t elems = (size_t)B_ * L_ * D_;  // 16M
  if (ws_size < 2 * elems * sizeof(f16)) return;

  // ws: proj f16 (32MB) | xT f16 (32MB); both dead after last PV -> reused as
  //     f32 bounce buffer for the final expand.
  // out timeline: {x16 32MB, W16 2MB} -> per chunk: S f32 (32MB) at [0,32M),
  //     compacted in place to P16 (lda 4096); O16 f16 accumulates at [32M,64M);
  //     finally expand -> ws -> copy -> out f32.
  f16* proj = (f16*)d_ws;
  f16* xT = proj + elems;
  f16* x16 = (f16*)d_out;
  f16* W16 = x16 + elems;
  float* Sf = (float*)d_out;                       // [B][512][2048] f32 chunk
  f16* P16 = (f16*)d_out;                          // same storage, lda 4096
  f16* O16 = (f16*)d_out + 16 * 1024 * 1024;       // [B][L][D] f16 at +32MB
  float* bounce = (float*)d_ws;

  transpose_kernel<<<dim3(L_ / 32, D_ / 32, B_), 256, 0, stream>>>(x, xT, x16);
  wcast_kernel<<<dim3((D_ * D_) / (256 * 8)), 256, 0, stream>>>(W, W16);

  // proj = relu(x16 @ W16^T + b): M=16384, N=1024, K=1024. mTiles=128, Z=1.
  gemm128_kernel<0><<<dim3((D_ / 128) * 128), 256, 0, stream>>>(
      x16, W16, (void*)proj, D_, D_, D_, D_, 128, 128,
      0, 0, 0, 0, bias, nullptr);

  for (int c = 0; c < 4; ++c) {
    const int rowOff = c * CH_;
    // S chunk = proj[rows rowOff..rowOff+511] @ proj^T : M=512, N=2048, K=1024.
    gemm128_kernel<1><<<dim3((L_ / 128) * 32), 256, 0, stream>>>(
        proj + (size_t)rowOff * D_, proj, (void*)Sf, D_, D_, L_, D_, 4, 32,
        (size_t)L_ * D_, (size_t)L_ * D_, (size_t)CH_ * L_, rowOff,
        nullptr, xmask);

    // softmax + compact: 4096 rows (8 batches x 512)
    softmax_kernel<<<dim3(B_ * CH_), 256, 0, stream>>>(Sf);

    // O16 chunk = P16 @ xT^T : M=512, N=1024, K=2048. lda=4096 (compacted).
    gemm128_kernel<2><<<dim3((D_ / 128) * 32), 256, 0, stream>>>(
        P16, xT, (void*)(O16 + (size_t)rowOff * D_), 2 * L_, L_, D_, L_, 4, 32,
        (size_t)CH_ * 2 * L_, (size_t)D_ * L_, (size_t)L_ * D_, 0,
        nullptr, nullptr);
  }

  // out f32 = (float)O16, bounced through ws (no overlap races).
  expand_kernel<<<dim3((B_ * L_ * D_) / (256 * 8)), 256, 0, stream>>>(O16, bounce);
  copy_kernel<<<dim3((B_ * L_ * D_) / (256 * 8)), 256, 0, stream>>>(bounce, out);
}

// Round 6
// 419.252 us; speedup vs baseline: 1.6886x; 1.1898x over previous
//
#include <hip/hip_runtime.h>
#include <hip/hip_bf16.h>

// R10: R9 + two structural fixes, GEMM inner loop untouched (proven 800 TF, 0 conflicts).
// (1) PV chunks merged in pairs: M=8192 -> 512 blocks = 2 blocks/CU (was 256 = 1/CU,
//     no partner block to hide the syncthreads vmcnt drain). Softmax now emits DENSE
//     P16 for chunks 0,1,2; chunk 3 stays in-place (lda 4096) and the PV template
//     selects (base,lda) per block (each 128-row block lies entirely in one chunk).
// (2) Tail 224 -> 128 MiB: PV23 writes O16 straight into dead proj (ws[0,16MiB));
//     copy O16-01 out[0,16M) -> ws[16,32M); one expand ws -> out (disjoint, race-free).
// Buffer timeline (MiB, out=64, ws=64: proj ws[0,32) xT ws[32,64)):
//   t1 transpose: x -> xT, x16(out[0,32))          t2 wcast: W16(out[32,34))
//   t3 proj GEMM: reads x16,W16 -> proj            [x16,W16 dead]
//   t4 S0 -> out[0,32) f32   t5 sm0: P0 -> out[32,48) dense   [S0 dead]
//   t6 S1 -> out[0,32)       t7 sm1: P1 -> out[48,64) dense   [S1 dead]
//   t8 PV01 (A=P0|P1): O16-01 -> out[0,16)                    [P0,P1 dead]
//   t9 S2 -> out[16,48)      t10 sm2: P2 -> out[48,64) dense  [S2 dead]
//   t11 S3 -> out[16,48)     [proj dead]  t12 sm3: P3 in-place lda4096
//   t13 PV23 (A=P2 lda2048 | P3 lda4096): O16-23 -> ws[0,16)  [xT,P2,P3 dead]
//   t14 copy out[0,16) -> ws[16,32)   t15 expand ws[0,32) -> out f32 [0,64)

typedef _Float16 f16;
typedef float f32x4 __attribute__((ext_vector_type(4)));
typedef _Float16 f16x8 __attribute__((ext_vector_type(8)));

#define MFMAH(A, B, C) __builtin_amdgcn_mfma_f32_16x16x32_f16((A), (B), (C), 0, 0, 0)

static constexpr int B_ = 8;
static constexpr int L_ = 2048;
static constexpr int D_ = 1024;
static constexpr int CH_ = 512;  // rows per batch per chunk

__device__ __forceinline__ void gload16(const f16* g, f16* l) {
  __builtin_amdgcn_global_load_lds(
      (const __attribute__((address_space(1))) void*)g,
      (__attribute__((address_space(3))) void*)l, 16, 0, 0);
}

// ---------------- K0: transpose x -> xT f16, plus x16 f16 ----------------
__global__ __launch_bounds__(256) void transpose_kernel(const float* __restrict__ x,
                                                        f16* __restrict__ xT,
                                                        f16* __restrict__ x16) {
  __shared__ f16 t[32][40];
  const int b = blockIdx.z;
  const int j0 = blockIdx.x << 5, d0 = blockIdx.y << 5;
  const int tid = threadIdx.x;
  const int r = tid >> 3, c = (tid & 7) << 2;
  float4 v = *(const float4*)&x[((size_t)(b * L_ + j0 + r)) * D_ + d0 + c];
  t[r][c + 0] = (f16)v.x; t[r][c + 1] = (f16)v.y;
  t[r][c + 2] = (f16)v.z; t[r][c + 3] = (f16)v.w;
  union { f16 h[4]; uint2 u; } xc;
  xc.h[0] = (f16)v.x; xc.h[1] = (f16)v.y;
  xc.h[2] = (f16)v.z; xc.h[3] = (f16)v.w;
  *(uint2*)&x16[((size_t)(b * L_ + j0 + r)) * D_ + d0 + c] = xc.u;
  __syncthreads();
  union { f16 h[4]; uint2 u; } o;
  o.h[0] = t[c + 0][r]; o.h[1] = t[c + 1][r];
  o.h[2] = t[c + 2][r]; o.h[3] = t[c + 3][r];
  *(uint2*)&xT[((size_t)(b * D_ + d0 + r)) * L_ + j0 + c] = o.u;
}

// ---------------- K0b: W f32 -> W16 ----------------
__global__ __launch_bounds__(256) void wcast_kernel(const float* __restrict__ W,
                                                    f16* __restrict__ W16) {
  const int i = (blockIdx.x * 256 + threadIdx.x) << 3;
  float4 a = *(const float4*)&W[i];
  float4 c = *(const float4*)&W[i + 4];
  union { f16 h[8]; uint4 u; } H;
  H.h[0] = (f16)a.x; H.h[1] = (f16)a.y; H.h[2] = (f16)a.z; H.h[3] = (f16)a.w;
  H.h[4] = (f16)c.x; H.h[5] = (f16)c.y; H.h[6] = (f16)c.z; H.h[7] = (f16)c.w;
  *(uint4*)&W16[i] = H.u;
}

// ---------------- Template GEMM: C = A(MxK) @ B(NxK)^T ----------------
// MODE 0: proj (bias+relu, f16 C). MODE 1: S chunk (f32 C, diag+mask).
// MODE 2: PV merged pair (f16 C); per-block A-source select: local m0<512 ->
//         (A,lda,aBatch), else (A1,lda1,a1Batch) with row (m0-512).
// 1-D grid: bid = nt*nbz + z*mTiles + mt -> bid%8 constant across nt for a
// fixed (z,mt): A-panel stays on one XCD L2 under round-robin dispatch.
template <int MODE>
__global__ __launch_bounds__(256, 2) void gemm128_kernel(
    const f16* __restrict__ A, const f16* __restrict__ A1,
    const f16* __restrict__ Bm, void* __restrict__ Cv,
    int lda, int lda1, int ldb, int ldc, int K, int mTiles, int nbz,
    size_t aBatch, size_t a1Batch, size_t bBatch, size_t cBatch, int rowOff,
    const float* __restrict__ bias, const int* __restrict__ xmask) {
  const int bid = blockIdx.x;
  const int nt = bid / nbz;
  const int rem = bid - nt * nbz;
  const int z = rem / mTiles;
  const int mt = rem - z * mTiles;
  const int m0 = mt << 7, n0 = nt << 7;

  const f16* Ab;
  int ldA;
  if (MODE == 2 && m0 >= CH_) {
    Ab = A1 + (size_t)z * a1Batch + (size_t)(m0 - CH_) * lda1;
    ldA = lda1;
  } else {
    Ab = A + (size_t)z * aBatch + (size_t)m0 * lda;
    ldA = lda;
  }
  const f16* Bb = Bm + (size_t)z * bBatch;

  __shared__ f16 As[128 * 64], Bs[128 * 64];

  const int tid = threadIdx.x;
  const int w = tid >> 6, lane = tid & 63;
  const int wr = w >> 1, wc = w & 1;
  const int quad = lane >> 4, l16 = lane & 15;

  const int srow0 = w << 5;
  const int lrow = lane >> 3;   // 0..7
  const int lchunk = lane & 7;  // 16B chunk 0..7

  f32x4 acc[4][4];
#pragma unroll
  for (int i = 0; i < 4; ++i)
#pragma unroll
    for (int j = 0; j < 4; ++j) acc[i][j] = (f32x4){0.f, 0.f, 0.f, 0.f};

  for (int kc = 0; kc < K; kc += 64) {
#pragma unroll
    for (int u = 0; u < 4; ++u) {
      const int r = srow0 + (u << 3) + lrow;
      const int ca = (lchunk ^ (r & 7)) << 3;  // pre-swizzled source chunk
      gload16(&Ab[(size_t)r * ldA + kc + ca], &As[(srow0 + (u << 3)) << 6]);
      gload16(&Bb[(size_t)(n0 + r) * ldb + kc + ca], &Bs[(srow0 + (u << 3)) << 6]);
    }
    __syncthreads();  // drains vmcnt -> staged data visible

    f16x8 af[4], bf[4];
#pragma unroll
    for (int h = 0; h < 2; ++h) {
#pragma unroll
      for (int i = 0; i < 4; ++i) {
        const int ra = (wr << 6) + (i << 4) + l16;
        af[i] = *(const f16x8*)&As[(ra << 6) + ((((h << 2) + quad) ^ (ra & 7)) << 3)];
        const int rb = (wc << 6) + (i << 4) + l16;
        bf[i] = *(const f16x8*)&Bs[(rb << 6) + ((((h << 2) + quad) ^ (rb & 7)) << 3)];
      }
#pragma unroll
      for (int i = 0; i < 4; ++i)
#pragma unroll
        for (int j = 0; j < 4; ++j) acc[i][j] = MFMAH(af[i], bf[j], acc[i][j]);
    }
    __syncthreads();
  }

#pragma unroll
  for (int j = 0; j < 4; ++j) {
    const int n = n0 + (wc << 6) + (j << 4) + l16;
    float bv = 0.f;
    bool msk = false;
    if (MODE == 0) bv = bias[n];
    if (MODE == 1) msk = (xmask[z * L_ + n] != 0);
#pragma unroll
    for (int i = 0; i < 4; ++i) {
      const int mb = m0 + (wr << 6) + (i << 4) + (quad << 2);
#pragma unroll
      for (int r = 0; r < 4; ++r) {
        float v = acc[i][j][r];
        if (MODE == 1) {
          if (rowOff + mb + r == n) v = 0.f;  // diagonal zero
          if (msk) v = -1e30f;                // padding mask
          ((float*)Cv + (size_t)z * cBatch)[(size_t)(mb + r) * ldc + n] = v;
        } else if (MODE == 0) {
          ((f16*)Cv)[(size_t)(mb + r) * ldc + n] = (f16)fmaxf(v + bv, 0.f);
        } else {
          ((f16*)Cv + (size_t)z * cBatch)[(size_t)(mb + r) * ldc + n] = (f16)v;
        }
      }
    }
  }
}

// ---------------- Row softmax: f32 row -> normalized f16 row at dst ----------------
// dstStride in f16 elems: 2048 = dense separate buffer; 4096 = in-place compact
// (safe: one block owns the row; all S reads precede the P write).
__global__ __launch_bounds__(256) void softmax_kernel(const float* __restrict__ S,
                                                      f16* __restrict__ P,
                                                      int dstStride) {
  const size_t row = blockIdx.x;
  const float* Sp = S + row * 2048;
  f16* Pp = P + row * (size_t)dstStride;
  const int tid = threadIdx.x;
  const float4 sA = *(const float4*)&Sp[tid * 8];
  const float4 sB = *(const float4*)&Sp[tid * 8 + 4];
  float f[8];
  f[0] = sA.x; f[1] = sA.y; f[2] = sA.z; f[3] = sA.w;
  f[4] = sB.x; f[5] = sB.y; f[6] = sB.z; f[7] = sB.w;
  float mx = fmaxf(fmaxf(fmaxf(f[0], f[1]), fmaxf(f[2], f[3])),
                   fmaxf(fmaxf(f[4], f[5]), fmaxf(f[6], f[7])));
#pragma unroll
  for (int off = 1; off < 64; off <<= 1) mx = fmaxf(mx, __shfl_xor(mx, off));
  __shared__ float redm[4], reds[4];
  const int wv = tid >> 6;
  if ((tid & 63) == 0) redm[wv] = mx;
  __syncthreads();
  mx = fmaxf(fmaxf(redm[0], redm[1]), fmaxf(redm[2], redm[3]));
  float s = 0.f;
#pragma unroll
  for (int i = 0; i < 8; ++i) { f[i] = __expf(f[i] - mx); s += f[i]; }
#pragma unroll
  for (int off = 1; off < 64; off <<= 1) s += __shfl_xor(s, off);
  if ((tid & 63) == 0) reds[wv] = s;
  __syncthreads();
  s = (reds[0] + reds[1]) + (reds[2] + reds[3]);
  const float inv = 1.0f / s;
  f16x8 o;
#pragma unroll
  for (int i = 0; i < 8; ++i) o[i] = (f16)(f[i] * inv);
  *(f16x8*)&Pp[tid * 8] = o;
}

// ---------------- 16-MiB raw copy (uint4 granular) ----------------
__global__ __launch_bounds__(256) void copy16_kernel(const uint4* __restrict__ src,
                                                     uint4* __restrict__ dst) {
  const size_t i = (size_t)blockIdx.x * 256 + threadIdx.x;
  dst[i] = src[i];
}

// ---------------- Expand: O16 halves in ws -> out f32 ----------------
// ws f16 view: [0, 8M) = rows 1024..2047 (O16-23), [8M, 16M) = rows 0..1023
// (O16-01), each laid out [b][1024 rows][1024] f16.
__global__ __launch_bounds__(256) void expand_kernel(const f16* __restrict__ wsf,
                                                     float* __restrict__ out) {
  const size_t e = ((size_t)blockIdx.x * 256 + threadIdx.x) << 3;
  const int b = (int)(e >> 21);
  const int rem = (int)(e & ((1u << 21) - 1));
  const int r = rem >> 10;
  const int d = rem & 1023;
  const f16* src = (r < 1024)
      ? wsf + (8u << 20) + ((size_t)b << 20) + ((size_t)r << 10) + d
      : wsf + ((size_t)b << 20) + ((size_t)(r - 1024) << 10) + d;
  f16x8 v = *(const f16x8*)src;
  float4 a, c;
  a.x = (float)v[0]; a.y = (float)v[1]; a.z = (float)v[2]; a.w = (float)v[3];
  c.x = (float)v[4]; c.y = (float)v[5]; c.z = (float)v[6]; c.w = (float)v[7];
  *(float4*)&out[e] = a;
  *(float4*)&out[e + 4] = c;
}

extern "C" void kernel_launch(void* const* d_in, const int* in_sizes, int n_in,
                              void* d_out, int out_size, void* d_ws, size_t ws_size,
                              hipStream_t stream) {
  const float* x = (const float*)d_in[0];
  const int* xmask = (const int*)d_in[1];
  const float* W = (const float*)d_in[2];
  const float* bias = (const float*)d_in[3];
  float* out = (float*)d_out;

  const size_t elems = (size_t)B_ * L_ * D_;  // 16M
  if (ws_size < 2 * elems * sizeof(f16)) return;

  const size_t MiB = 1024 * 1024;
  f16* proj = (f16*)d_ws;                          // ws[0,32MiB)
  f16* xT = proj + elems;                          // ws[32,64MiB)
  f16* x16 = (f16*)d_out;                          // out[0,32MiB)
  f16* W16 = x16 + elems;                          // out[32,34MiB)
  float* Sf01 = (float*)d_out;                     // out[0,32MiB) f32 chunk
  float* Sf23 = (float*)((char*)d_out + 16 * MiB); // out[16,48MiB) f32 chunk
  f16* P0 = (f16*)((char*)d_out + 32 * MiB);       // dense [4096][2048]
  f16* P1 = (f16*)((char*)d_out + 48 * MiB);
  f16* P2 = P1;                                    // reuses P1 slot (dead)
  f16* P3 = (f16*)Sf23;                            // in-place, lda 4096
  f16* O01 = (f16*)d_out;                          // out[0,16MiB)
  f16* O23 = (f16*)d_ws;                           // ws[0,16MiB) (proj dead)

  transpose_kernel<<<dim3(L_ / 32, D_ / 32, B_), 256, 0, stream>>>(x, xT, x16);
  wcast_kernel<<<dim3((D_ * D_) / (256 * 8)), 256, 0, stream>>>(W, W16);

  // proj = relu(x16 @ W16^T + b): M=16384, N=1024, K=1024.
  gemm128_kernel<0><<<dim3((D_ / 128) * 128), 256, 0, stream>>>(
      x16, nullptr, W16, (void*)proj, D_, 0, D_, D_, D_, 128, 128,
      0, 0, 0, 0, 0, bias, nullptr);

  float* Sdst[4] = {Sf01, Sf01, Sf23, Sf23};
  f16* Pdst[4] = {P0, P1, P2, P3};
  for (int c = 0; c < 4; ++c) {
    // S chunk: M=512/batch (rows 512c..), N=2048, K=1024, Z=8 -> 512 blocks.
    gemm128_kernel<1><<<dim3((L_ / 128) * 32), 256, 0, stream>>>(
        proj + (size_t)c * CH_ * D_, nullptr, proj, (void*)Sdst[c],
        D_, 0, D_, L_, D_, 4, 32,
        (size_t)L_ * D_, 0, (size_t)L_ * D_, (size_t)CH_ * L_, c * CH_,
        nullptr, xmask);
    // softmax: 4096 rows; dense P for c<3, in-place lda 4096 for c==3.
    softmax_kernel<<<dim3(B_ * CH_), 256, 0, stream>>>(
        Sdst[c], Pdst[c], c == 3 ? 2 * L_ : L_);
    if (c == 1) {
      // PV01: M=1024/batch over {P0,P1}, N=1024, K=2048 -> 512 blocks, 2/CU.
      gemm128_kernel<2><<<dim3((D_ / 128) * 64), 256, 0, stream>>>(
          P0, P1, xT, (void*)O01, L_, L_, L_, D_, L_, 8, 64,
          (size_t)CH_ * L_, (size_t)CH_ * L_, (size_t)D_ * L_, (size_t)1024 * D_,
          0, nullptr, nullptr);
    }
  }
  // PV23: A = P2 dense lda 2048 | P3 in-place lda 4096; O16-23 -> ws[0,16MiB).
  gemm128_kernel<2><<<dim3((D_ / 128) * 64), 256, 0, stream>>>(
      P2, P3, xT, (void*)O23, L_, 2 * L_, L_, D_, L_, 8, 64,
      (size_t)CH_ * L_, (size_t)CH_ * 2 * L_, (size_t)D_ * L_, (size_t)1024 * D_,
      0, nullptr, nullptr);

  // O16-01 out[0,16MiB) -> ws[16,32MiB), then one race-free expand ws -> out.
  copy16_kernel<<<dim3(4096), 256, 0, stream>>>(
      (const uint4*)O01, (uint4*)((char*)d_ws + 16 * MiB));
  expand_kernel<<<dim3((B_ * L_ * D_) / (256 * 8)), 256, 0, stream>>>(
      (const f16*)d_ws, out);
}

// Round 7
// 382.630 us; speedup vs baseline: 1.8502x; 1.0957x over previous
//
#include <hip/hip_runtime.h>
#include <hip/hip_bf16.h>

// R11: R10 + batch-pinned XCD mapping for all GEMMs. PV counters showed
// FETCH=144MiB vs 64MiB unique (xT streamed across all 8 XCDs because
// bid%8=mt). New 1-D decomposition: z=bid&7 (XCD key under round-robin),
// mt=(bid>>3)%mTiles, nt=(bid>>3)/mTiles -> per-XCD working set is one
// batch's A+B (8MiB PV, 5MiB S); co-resident pace-aligned blocks share each
// 64-wide K slice through L2. GEMM inner loop / swizzle / epilogues and the
// whole R10 buffer choreography are UNCHANGED.
// Buffer timeline (MiB, out=64, ws=64: proj ws[0,32) xT ws[32,64)):
//   t1 transpose: x -> xT, x16(out[0,32))          t2 wcast: W16(out[32,34))
//   t3 proj GEMM: reads x16,W16 -> proj            [x16,W16 dead]
//   t4 S0 -> out[0,32) f32   t5 sm0: P0 -> out[32,48) dense   [S0 dead]
//   t6 S1 -> out[0,32)       t7 sm1: P1 -> out[48,64) dense   [S1 dead]
//   t8 PV01 (A=P0|P1): O16-01 -> out[0,16)                    [P0,P1 dead]
//   t9 S2 -> out[16,48)      t10 sm2: P2 -> out[48,64) dense  [S2 dead]
//   t11 S3 -> out[16,48)     [proj dead]  t12 sm3: P3 in-place lda4096
//   t13 PV23 (A=P2 lda2048 | P3 lda4096): O16-23 -> ws[0,16)  [xT,P2,P3 dead]
//   t14 copy out[0,16) -> ws[16,32)   t15 expand ws[0,32) -> out f32 [0,64)

typedef _Float16 f16;
typedef float f32x4 __attribute__((ext_vector_type(4)));
typedef _Float16 f16x8 __attribute__((ext_vector_type(8)));

#define MFMAH(A, B, C) __builtin_amdgcn_mfma_f32_16x16x32_f16((A), (B), (C), 0, 0, 0)

static constexpr int B_ = 8;
static constexpr int L_ = 2048;
static constexpr int D_ = 1024;
static constexpr int CH_ = 512;  // rows per batch per chunk

__device__ __forceinline__ void gload16(const f16* g, f16* l) {
  __builtin_amdgcn_global_load_lds(
      (const __attribute__((address_space(1))) void*)g,
      (__attribute__((address_space(3))) void*)l, 16, 0, 0);
}

// ---------------- K0: transpose x -> xT f16, plus x16 f16 ----------------
__global__ __launch_bounds__(256) void transpose_kernel(const float* __restrict__ x,
                                                        f16* __restrict__ xT,
                                                        f16* __restrict__ x16) {
  __shared__ f16 t[32][40];
  const int b = blockIdx.z;
  const int j0 = blockIdx.x << 5, d0 = blockIdx.y << 5;
  const int tid = threadIdx.x;
  const int r = tid >> 3, c = (tid & 7) << 2;
  float4 v = *(const float4*)&x[((size_t)(b * L_ + j0 + r)) * D_ + d0 + c];
  t[r][c + 0] = (f16)v.x; t[r][c + 1] = (f16)v.y;
  t[r][c + 2] = (f16)v.z; t[r][c + 3] = (f16)v.w;
  union { f16 h[4]; uint2 u; } xc;
  xc.h[0] = (f16)v.x; xc.h[1] = (f16)v.y;
  xc.h[2] = (f16)v.z; xc.h[3] = (f16)v.w;
  *(uint2*)&x16[((size_t)(b * L_ + j0 + r)) * D_ + d0 + c] = xc.u;
  __syncthreads();
  union { f16 h[4]; uint2 u; } o;
  o.h[0] = t[c + 0][r]; o.h[1] = t[c + 1][r];
  o.h[2] = t[c + 2][r]; o.h[3] = t[c + 3][r];
  *(uint2*)&xT[((size_t)(b * D_ + d0 + r)) * L_ + j0 + c] = o.u;
}

// ---------------- K0b: W f32 -> W16 ----------------
__global__ __launch_bounds__(256) void wcast_kernel(const float* __restrict__ W,
                                                    f16* __restrict__ W16) {
  const int i = (blockIdx.x * 256 + threadIdx.x) << 3;
  float4 a = *(const float4*)&W[i];
  float4 c = *(const float4*)&W[i + 4];
  union { f16 h[8]; uint4 u; } H;
  H.h[0] = (f16)a.x; H.h[1] = (f16)a.y; H.h[2] = (f16)a.z; H.h[3] = (f16)a.w;
  H.h[4] = (f16)c.x; H.h[5] = (f16)c.y; H.h[6] = (f16)c.z; H.h[7] = (f16)c.w;
  *(uint4*)&W16[i] = H.u;
}

// ---------------- Template GEMM: C = A(MxK) @ B(NxK)^T ----------------
// MODE 0: proj (bias+relu, f16 C). MODE 1: S chunk (f32 C, diag+mask).
// MODE 2: PV merged pair (f16 C); per-block A-source select: local m0<512 ->
//         (A,lda,aBatch), else (A1,lda1,a1Batch) with row (m0-512).
// 1-D grid, batch-pinned XCDs: z=bid&7 (constant per XCD under round-robin),
// mt=(bid>>3)%mTiles, nt=(bid>>3)/mTiles. Per-XCD working set = one batch's
// A+B; co-resident blocks share each K slice via L2.
template <int MODE>
__global__ __launch_bounds__(256, 2) void gemm128_kernel(
    const f16* __restrict__ A, const f16* __restrict__ A1,
    const f16* __restrict__ Bm, void* __restrict__ Cv,
    int lda, int lda1, int ldb, int ldc, int K, int mTiles,
    size_t aBatch, size_t a1Batch, size_t bBatch, size_t cBatch, int rowOff,
    const float* __restrict__ bias, const int* __restrict__ xmask) {
  const int bid = blockIdx.x;
  const int z = bid & 7;
  const int rest = bid >> 3;
  const int mt = rest % mTiles;
  const int nt = rest / mTiles;
  const int m0 = mt << 7, n0 = nt << 7;

  const f16* Ab;
  int ldA;
  if (MODE == 2 && m0 >= CH_) {
    Ab = A1 + (size_t)z * a1Batch + (size_t)(m0 - CH_) * lda1;
    ldA = lda1;
  } else {
    Ab = A + (size_t)z * aBatch + (size_t)m0 * lda;
    ldA = lda;
  }
  const f16* Bb = Bm + (size_t)z * bBatch;

  __shared__ f16 As[128 * 64], Bs[128 * 64];

  const int tid = threadIdx.x;
  const int w = tid >> 6, lane = tid & 63;
  const int wr = w >> 1, wc = w & 1;
  const int quad = lane >> 4, l16 = lane & 15;

  const int srow0 = w << 5;
  const int lrow = lane >> 3;   // 0..7
  const int lchunk = lane & 7;  // 16B chunk 0..7

  f32x4 acc[4][4];
#pragma unroll
  for (int i = 0; i < 4; ++i)
#pragma unroll
    for (int j = 0; j < 4; ++j) acc[i][j] = (f32x4){0.f, 0.f, 0.f, 0.f};

  for (int kc = 0; kc < K; kc += 64) {
#pragma unroll
    for (int u = 0; u < 4; ++u) {
      const int r = srow0 + (u << 3) + lrow;
      const int ca = (lchunk ^ (r & 7)) << 3;  // pre-swizzled source chunk
      gload16(&Ab[(size_t)r * ldA + kc + ca], &As[(srow0 + (u << 3)) << 6]);
      gload16(&Bb[(size_t)(n0 + r) * ldb + kc + ca], &Bs[(srow0 + (u << 3)) << 6]);
    }
    __syncthreads();  // drains vmcnt -> staged data visible

    f16x8 af[4], bf[4];
#pragma unroll
    for (int h = 0; h < 2; ++h) {
#pragma unroll
      for (int i = 0; i < 4; ++i) {
        const int ra = (wr << 6) + (i << 4) + l16;
        af[i] = *(const f16x8*)&As[(ra << 6) + ((((h << 2) + quad) ^ (ra & 7)) << 3)];
        const int rb = (wc << 6) + (i << 4) + l16;
        bf[i] = *(const f16x8*)&Bs[(rb << 6) + ((((h << 2) + quad) ^ (rb & 7)) << 3)];
      }
#pragma unroll
      for (int i = 0; i < 4; ++i)
#pragma unroll
        for (int j = 0; j < 4; ++j) acc[i][j] = MFMAH(af[i], bf[j], acc[i][j]);
    }
    __syncthreads();
  }

#pragma unroll
  for (int j = 0; j < 4; ++j) {
    const int n = n0 + (wc << 6) + (j << 4) + l16;
    float bv = 0.f;
    bool msk = false;
    if (MODE == 0) bv = bias[n];
    if (MODE == 1) msk = (xmask[z * L_ + n] != 0);
#pragma unroll
    for (int i = 0; i < 4; ++i) {
      const int mb = m0 + (wr << 6) + (i << 4) + (quad << 2);
#pragma unroll
      for (int r = 0; r < 4; ++r) {
        float v = acc[i][j][r];
        if (MODE == 1) {
          if (rowOff + mb + r == n) v = 0.f;  // diagonal zero
          if (msk) v = -1e30f;                // padding mask
          ((float*)Cv + (size_t)z * cBatch)[(size_t)(mb + r) * ldc + n] = v;
        } else if (MODE == 0) {
          ((f16*)Cv + (size_t)z * cBatch)[(size_t)(mb + r) * ldc + n] =
              (f16)fmaxf(v + bv, 0.f);
        } else {
          ((f16*)Cv + (size_t)z * cBatch)[(size_t)(mb + r) * ldc + n] = (f16)v;
        }
      }
    }
  }
}

// ---------------- Row softmax: f32 row -> normalized f16 row at dst ----------------
// dstStride in f16 elems: 2048 = dense separate buffer; 4096 = in-place compact
// (safe: one block owns the row; all S reads precede the P write).
__global__ __launch_bounds__(256) void softmax_kernel(const float* __restrict__ S,
                                                      f16* __restrict__ P,
                                                      int dstStride) {
  const size_t row = blockIdx.x;
  const float* Sp = S + row * 2048;
  f16* Pp = P + row * (size_t)dstStride;
  const int tid = threadIdx.x;
  const float4 sA = *(const float4*)&Sp[tid * 8];
  const float4 sB = *(const float4*)&Sp[tid * 8 + 4];
  float f[8];
  f[0] = sA.x; f[1] = sA.y; f[2] = sA.z; f[3] = sA.w;
  f[4] = sB.x; f[5] = sB.y; f[6] = sB.z; f[7] = sB.w;
  float mx = fmaxf(fmaxf(fmaxf(f[0], f[1]), fmaxf(f[2], f[3])),
                   fmaxf(fmaxf(f[4], f[5]), fmaxf(f[6], f[7])));
#pragma unroll
  for (int off = 1; off < 64; off <<= 1) mx = fmaxf(mx, __shfl_xor(mx, off));
  __shared__ float redm[4], reds[4];
  const int wv = tid >> 6;
  if ((tid & 63) == 0) redm[wv] = mx;
  __syncthreads();
  mx = fmaxf(fmaxf(redm[0], redm[1]), fmaxf(redm[2], redm[3]));
  float s = 0.f;
#pragma unroll
  for (int i = 0; i < 8; ++i) { f[i] = __expf(f[i] - mx); s += f[i]; }
#pragma unroll
  for (int off = 1; off < 64; off <<= 1) s += __shfl_xor(s, off);
  if ((tid & 63) == 0) reds[wv] = s;
  __syncthreads();
  s = (reds[0] + reds[1]) + (reds[2] + reds[3]);
  const float inv = 1.0f / s;
  f16x8 o;
#pragma unroll
  for (int i = 0; i < 8; ++i) o[i] = (f16)(f[i] * inv);
  *(f16x8*)&Pp[tid * 8] = o;
}

// ---------------- 16-MiB raw copy (uint4 granular) ----------------
__global__ __launch_bounds__(256) void copy16_kernel(const uint4* __restrict__ src,
                                                     uint4* __restrict__ dst) {
  const size_t i = (size_t)blockIdx.x * 256 + threadIdx.x;
  dst[i] = src[i];
}

// ---------------- Expand: O16 halves in ws -> out f32 ----------------
// ws f16 view: [0, 8M) = rows 1024..2047 (O16-23), [8M, 16M) = rows 0..1023
// (O16-01), each laid out [b][1024 rows][1024] f16.
__global__ __launch_bounds__(256) void expand_kernel(const f16* __restrict__ wsf,
                                                     float* __restrict__ out) {
  const size_t e = ((size_t)blockIdx.x * 256 + threadIdx.x) << 3;
  const int b = (int)(e >> 21);
  const int rem = (int)(e & ((1u << 21) - 1));
  const int r = rem >> 10;
  const int d = rem & 1023;
  const f16* src = (r < 1024)
      ? wsf + (8u << 20) + ((size_t)b << 20) + ((size_t)r << 10) + d
      : wsf + ((size_t)b << 20) + ((size_t)(r - 1024) << 10) + d;
  f16x8 v = *(const f16x8*)src;
  float4 a, c;
  a.x = (float)v[0]; a.y = (float)v[1]; a.z = (float)v[2]; a.w = (float)v[3];
  c.x = (float)v[4]; c.y = (float)v[5]; c.z = (float)v[6]; c.w = (float)v[7];
  *(float4*)&out[e] = a;
  *(float4*)&out[e + 4] = c;
}

extern "C" void kernel_launch(void* const* d_in, const int* in_sizes, int n_in,
                              void* d_out, int out_size, void* d_ws, size_t ws_size,
                              hipStream_t stream) {
  const float* x = (const float*)d_in[0];
  const int* xmask = (const int*)d_in[1];
  const float* W = (const float*)d_in[2];
  const float* bias = (const float*)d_in[3];
  float* out = (float*)d_out;

  const size_t elems = (size_t)B_ * L_ * D_;  // 16M
  if (ws_size < 2 * elems * sizeof(f16)) return;

  const size_t MiB = 1024 * 1024;
  f16* proj = (f16*)d_ws;                          // ws[0,32MiB)
  f16* xT = proj + elems;                          // ws[32,64MiB)
  f16* x16 = (f16*)d_out;                          // out[0,32MiB)
  f16* W16 = x16 + elems;                          // out[32,34MiB)
  float* Sf01 = (float*)d_out;                     // out[0,32MiB) f32 chunk
  float* Sf23 = (float*)((char*)d_out + 16 * MiB); // out[16,48MiB) f32 chunk
  f16* P0 = (f16*)((char*)d_out + 32 * MiB);       // dense [4096][2048]
  f16* P1 = (f16*)((char*)d_out + 48 * MiB);
  f16* P2 = P1;                                    // reuses P1 slot (dead)
  f16* P3 = (f16*)Sf23;                            // in-place, lda 4096
  f16* O01 = (f16*)d_out;                          // out[0,16MiB)
  f16* O23 = (f16*)d_ws;                           // ws[0,16MiB) (proj dead)

  transpose_kernel<<<dim3(L_ / 32, D_ / 32, B_), 256, 0, stream>>>(x, xT, x16);
  wcast_kernel<<<dim3((D_ * D_) / (256 * 8)), 256, 0, stream>>>(W, W16);

  // proj = relu(x16 @ W16^T + b): M=16384 as 8 pseudo-batches x 2048 rows,
  // N=1024, K=1024. mTiles=16, nTiles=8 -> 1024 blocks; W16 shared (bBatch 0).
  gemm128_kernel<0><<<dim3(16 * 8 * 8), 256, 0, stream>>>(
      x16, nullptr, W16, (void*)proj, D_, 0, D_, D_, D_, 16,
      (size_t)2048 * D_, 0, 0, (size_t)2048 * D_, 0, bias, nullptr);

  float* Sdst[4] = {Sf01, Sf01, Sf23, Sf23};
  f16* Pdst[4] = {P0, P1, P2, P3};
  for (int c = 0; c < 4; ++c) {
    // S chunk: M=512/batch (rows 512c..), N=2048, K=1024, Z=8.
    // mTiles=4, nTiles=16 -> 512 blocks; per-XCD = proj[z] (4MiB) + chunk (1MiB).
    gemm128_kernel<1><<<dim3(4 * 16 * 8), 256, 0, stream>>>(
        proj + (size_t)c * CH_ * D_, nullptr, proj, (void*)Sdst[c],
        D_, 0, D_, L_, D_, 4,
        (size_t)L_ * D_, 0, (size_t)L_ * D_, (size_t)CH_ * L_, c * CH_,
        nullptr, xmask);
    // softmax: 4096 rows; dense P for c<3, in-place lda 4096 for c==3.
    softmax_kernel<<<dim3(B_ * CH_), 256, 0, stream>>>(
        Sdst[c], Pdst[c], c == 3 ? 2 * L_ : L_);
    if (c == 1) {
      // PV01: M=1024/batch over {P0,P1}, N=1024, K=2048.
      // mTiles=8, nTiles=8 -> 512 blocks; per-XCD = P[z] (4MiB) + xT[z] (4MiB).
      gemm128_kernel<2><<<dim3(8 * 8 * 8), 256, 0, stream>>>(
          P0, P1, xT, (void*)O01, L_, L_, L_, D_, L_, 8,
          (size_t)CH_ * L_, (size_t)CH_ * L_, (size_t)D_ * L_, (size_t)1024 * D_,
          0, nullptr, nullptr);
    }
  }
  // PV23: A = P2 dense lda 2048 | P3 in-place lda 4096; O16-23 -> ws[0,16MiB).
  gemm128_kernel<2><<<dim3(8 * 8 * 8), 256, 0, stream>>>(
      P2, P3, xT, (void*)O23, L_, 2 * L_, L_, D_, L_, 8,
      (size_t)CH_ * L_, (size_t)CH_ * 2 * L_, (size_t)D_ * L_, (size_t)1024 * D_,
      0, nullptr, nullptr);

  // O16-01 out[0,16MiB) -> ws[16,32MiB), then one race-free expand ws -> out.
  copy16_kernel<<<dim3(4096), 256, 0, stream>>>(
      (const uint4*)O01, (uint4*)((char*)d_ws + 16 * MiB));
  expand_kernel<<<dim3((B_ * L_ * D_) / (256 * 8)), 256, 0, stream>>>(
      (const f16*)d_ws, out);
}